// Round 4
// baseline (1342.589 us; speedup 1.0000x reference)
//
// v12: k_conv reverted to v10 exactly (2 px/thread, 462µs known-good).
// k_stats rewritten: lane-parallel channel chains — 16 blocks x 64 lanes,
// one channel per lane, each lane runs its own bit-exact (b,h,w) serial chain;
// 4 rotating 16xfloat4 register buffers give depth-3 global prefetch.
// No LDS, no barriers. FP sequence per channel identical to v8/v9.
#include <hip/hip_runtime.h>

#define OFF_PSUM   0UL            // 134217728 B  f32 psum[b][1024][32][32]
#define OFF_ALPHA  134217728UL    // 1024 B
#define OFF_INV    134218752UL    // 4096 B
#define OFF_BT     134222848UL    // 4096 B   (total 134.23 MB, proven fits)

// ---------------- K0a: alpha — LDS-staged, exact sequential chain ----------------
__global__ __launch_bounds__(256) void k_alpha(const float* __restrict__ w,
                                               float* __restrict__ alpha) {
#pragma clang fp contract(off)
    __shared__ float buf[2304];
    int co = blockIdx.x, t = threadIdx.x;
    const float* p = w + (size_t)co * 2304;
    for (int i = t; i < 2304; i += 256) buf[i] = p[i];
    __syncthreads();
    if (t == 0) {
        float s = 0.f;
#pragma unroll 16
        for (int k = 0; k < 2304; ++k) s = s + fabsf(buf[k]);
        alpha[co] = s / 2304.0f;
    }
}

// ---------------- K0b: transposed +-alpha table wsaT[((g*9+tap)*64+ci)*256+co] ----------------
__global__ __launch_bounds__(256) void k_wsaT(const float* __restrict__ w,
                                              const float* __restrict__ alpha,
                                              float* __restrict__ wsaT) {
    int item = blockIdx.x * 256 + threadIdx.x;     // 589824 items
    int co = item & 255;
    int rest = item >> 8;                           // 0..2303
    int ci = rest & 63;
    int t9 = rest >> 6;                             // 0..35
    int tap = t9 % 9, g = t9 / 9;
    float av = alpha[co];
    float wv = w[((size_t)co * 256 + g * 64 + ci) * 9 + tap];
    wsaT[item] = (wv >= 0.f) ? av : -av;           // exact +-alpha
}

// ---------------- K1: conv — v10: 2 px/thread, SGPR weights, 64 FMA per weight row ----------------
// block (b,g,band4): 8 waves x 32 co; thread = px (h,m) and (h+2,m); acc0/acc1[32]
__global__ __launch_bounds__(512, 4) void k_conv(const float* __restrict__ x,
                                                 const float* __restrict__ wsaT,
                                                 float* __restrict__ psum) {
#pragma clang fp contract(off)
    __shared__ float xs[6][34][68];
    int bx = blockIdx.x;
    int band = bx & 7, g = (bx >> 3) & 3, b = bx >> 5;   // 1024 blocks
    int t = threadIdx.x;

    const float* xg = x + (size_t)(b * 256 + g * 64) * 1024;
#pragma unroll 1
    for (int i = 0; i < 26; ++i) {                 // 6*34*64 = 13056 elements
        int idx = i * 512 + t;
        if (idx < 13056) {
            int ci = idx & 63, col = (idx >> 6) % 34, row = idx / 2176;
            int gr = band * 4 + row - 1, gc = col - 1;
            float v = (gr >= 0 && gr < 32 && gc >= 0 && gc < 32)
                        ? xg[(size_t)ci * 1024 + gr * 32 + gc] : 0.f;
            xs[row][col][ci] = v;
        }
    }
    __syncthreads();

    int wid = t >> 6, lane = t & 63;
    int r = lane >> 5, m = lane & 31;
    int h0 = band * 4 + r;                          // second px at h0+2
    int cobase = __builtin_amdgcn_readfirstlane(wid * 32);   // wave-uniform

    float acc0[32], acc1[32];
#pragma unroll
    for (int j = 0; j < 32; ++j) { acc0[j] = 0.f; acc1[j] = 0.f; }

#pragma unroll 1
    for (int kh = 0; kh < 3; ++kh)
#pragma unroll 1
        for (int kw = 0; kw < 3; ++kw) {
            int tap = kh * 3 + kw;
            const float* bp0 = &xs[r + kh][m + kw][0];
            const float* bp1 = &xs[r + 2 + kh][m + kw][0];
            // wave-uniform weight row base for this (g,tap): wsaT[...][ci][co]
            const float* wt = wsaT + (((size_t)(g * 9 + tap) * 64) << 8) + cobase;
#pragma unroll
            for (int c = 0; c < 4; ++c) {           // ci chunks of 16
                float xv0[16], xv1[16];
#pragma unroll
                for (int q = 0; q < 4; ++q) {
                    float4 a = *(const float4*)(bp0 + c * 16 + q * 4);
                    xv0[q * 4 + 0] = a.x; xv0[q * 4 + 1] = a.y;
                    xv0[q * 4 + 2] = a.z; xv0[q * 4 + 3] = a.w;
                    float4 d = *(const float4*)(bp1 + c * 16 + q * 4);
                    xv1[q * 4 + 0] = d.x; xv1[q * 4 + 1] = d.y;
                    xv1[q * 4 + 2] = d.z; xv1[q * 4 + 3] = d.w;
                }
#pragma unroll
                for (int ci = 0; ci < 16; ++ci) {   // per-acc chain order preserved
                    const float* wr = wt + ((c * 16 + ci) << 8);  // uniform -> s_load
#pragma unroll
                    for (int j = 0; j < 32; ++j)
                        acc0[j] = fmaf(xv0[ci], wr[j], acc0[j]);
#pragma unroll
                    for (int j = 0; j < 32; ++j)
                        acc1[j] = fmaf(xv1[ci], wr[j], acc1[j]);
                }
            }
        }

#pragma unroll
    for (int j = 0; j < 32; ++j) {
        int co = cobase + j;
        size_t rowo = ((size_t)b * 1024 + g * 256 + co) * 32;
        psum[(rowo + h0) * 32 + m]     = acc0[j];
        psum[(rowo + h0 + 2) * 32 + m] = acc1[j];
    }
}

// ---------------- K2: BN stats — lane-parallel channel chains ----------------
// 16 blocks x 64 lanes; lane owns channel ch = blk*64+lane. Each lane streams its
// channel's 32768 elems in exact (b,h,w) order through a depth-3 register pipeline
// (4 rotating buffers x 16 float4) and runs the bit-exact s = s + v chain.
__global__ __launch_bounds__(64, 1) void k_stats(const float* __restrict__ psum,
                                                 const float* __restrict__ gamma,
                                                 const float* __restrict__ beta,
                                                 float* __restrict__ invA,
                                                 float* __restrict__ btA) {
#pragma clang fp contract(off)
    int ch = blockIdx.x * 64 + threadIdx.x;
    const float* lb = psum + (size_t)ch * 1024;     // per-b stride is 1048576 floats

    // group g in [0,512): b = g>>4, intra-b offset = (g&15)*64 ; 16 float4 loads
#define LOADG(BUF, GI)                                                           \
    do { int _g = (GI);                                                          \
        const float* _p = lb + ((size_t)(_g >> 4) * 1048576) + ((_g & 15) * 64); \
        _Pragma("unroll")                                                        \
        for (int u = 0; u < 16; ++u) BUF[u] = *(const float4*)(_p + u * 4);      \
    } while (0)

#define ADDG(BUF)                                                                \
    do { _Pragma("unroll")                                                       \
        for (int u = 0; u < 16; ++u) {                                           \
            s = s + BUF[u].x; s = s + BUF[u].y;                                  \
            s = s + BUF[u].z; s = s + BUF[u].w; }                                \
    } while (0)

#define ADDVG(BUF)                                                               \
    do { _Pragma("unroll")                                                       \
        for (int u = 0; u < 16; ++u) {                                           \
            float d0 = BUF[u].x - mean; float q0 = d0 * d0; v = v + q0;          \
            float d1 = BUF[u].y - mean; float q1 = d1 * d1; v = v + q1;          \
            float d2 = BUF[u].z - mean; float q2 = d2 * d2; v = v + q2;          \
            float d3 = BUF[u].w - mean; float q3 = d3 * d3; v = v + q3; }        \
    } while (0)

    float4 P[16], Q[16], R[16], T[16];

    // ---- pass 1: mean (exact v8 chain order) ----
    float s = 0.f;
    LOADG(P, 0); LOADG(Q, 1); LOADG(R, 2);
#pragma unroll 1
    for (int g = 0; g < 512; g += 4) {
        LOADG(T, g + 3);
        ADDG(P);
        if (g + 4 < 512) { LOADG(P, g + 4); }
        ADDG(Q);
        if (g + 5 < 512) { LOADG(Q, g + 5); }
        ADDG(R);
        if (g + 6 < 512) { LOADG(R, g + 6); }
        ADDG(T);
    }
    float mean = s / 32768.0f;

    // ---- pass 2: var — d=p-mean; q=d*d; v=v+q in exact element order ----
    float v = 0.f;
    LOADG(P, 0); LOADG(Q, 1); LOADG(R, 2);
#pragma unroll 1
    for (int g = 0; g < 512; g += 4) {
        LOADG(T, g + 3);
        ADDVG(P);
        if (g + 4 < 512) { LOADG(P, g + 4); }
        ADDVG(Q);
        if (g + 5 < 512) { LOADG(Q, g + 5); }
        ADDVG(R);
        if (g + 6 < 512) { LOADG(R, g + 6); }
        ADDVG(T);
    }

    float var = v / 32768.0f;
    float sq = sqrtf(var + 1e-5f);
    float inv = 1.0f / sq;
    inv = inv * gamma[ch];
    float mb = mean * inv;
    invA[ch] = inv;
    btA[ch] = beta[ch] - mb;

#undef LOADG
#undef ADDG
#undef ADDVG
}

// ---------------- K3: BN apply + sign + merge + literal qrelu (unchanged, passed) ----------------
__global__ __launch_bounds__(256) void k_apply(const float* __restrict__ psum,
                                               const float* __restrict__ invA,
                                               const float* __restrict__ btA,
                                               float* __restrict__ out) {
#pragma clang fp contract(off)
    int idx = blockIdx.x * 256 + threadIdx.x;
    int w4 = (idx & 7) * 4;
    int hh = (idx >> 3) & 31;
    int co = (idx >> 8) & 255;
    int b  = idx >> 16;

    float s0 = 0.f, s1 = 0.f, s2 = 0.f, s3 = 0.f;
    for (int g = 0; g < 4; ++g) {
        int ch = g * 256 + co;
        const float4 p = *(const float4*)(psum + (((size_t)b * 1024 + ch) * 32 + hh) * 32 + w4);
        float iv = invA[ch], bt = btA[ch];
        float y0 = p.x * iv; y0 = y0 + bt;
        float y1 = p.y * iv; y1 = y1 + bt;
        float y2 = p.z * iv; y2 = y2 + bt;
        float y3 = p.w * iv; y3 = y3 + bt;
        s0 = s0 + ((y0 >= 0.f) ? 1.f : -1.f);
        s1 = s1 + ((y1 >= 0.f) ? 1.f : -1.f);
        s2 = s2 + ((y2 >= 0.f) ? 1.f : -1.f);
        s3 = s3 + ((y3 >= 0.f) ? 1.f : -1.f);
    }
    float4 q;
    {
        float u, rr, qq;
        u = s0 * 0.25f; u = fminf(fmaxf(u, 0.f), 1.f); rr = rintf(u * 15.f); qq = rr / 15.f; q.x = qq * 4.f;
        u = s1 * 0.25f; u = fminf(fmaxf(u, 0.f), 1.f); rr = rintf(u * 15.f); qq = rr / 15.f; q.y = qq * 4.f;
        u = s2 * 0.25f; u = fminf(fmaxf(u, 0.f), 1.f); rr = rintf(u * 15.f); qq = rr / 15.f; q.z = qq * 4.f;
        u = s3 * 0.25f; u = fminf(fmaxf(u, 0.f), 1.f); rr = rintf(u * 15.f); qq = rr / 15.f; q.w = qq * 4.f;
    }
    *(float4*)(out + (((size_t)b * 256 + co) * 32 + hh) * 32 + w4) = q;
}

extern "C" void kernel_launch(void* const* d_in, const int* in_sizes, int n_in,
                              void* d_out, int out_size, void* d_ws, size_t ws_size,
                              hipStream_t stream) {
    (void)in_sizes; (void)n_in; (void)out_size; (void)ws_size;
    const float* x     = (const float*)d_in[0];
    const float* w     = (const float*)d_in[1];
    const float* gamma = (const float*)d_in[2];
    const float* beta  = (const float*)d_in[3];
    float* out = (float*)d_out;
    char* ws = (char*)d_ws;
    float* psum  = (float*)(ws + OFF_PSUM);
    float* alpha = (float*)(ws + OFF_ALPHA);
    float* invA  = (float*)(ws + OFF_INV);
    float* btA   = (float*)(ws + OFF_BT);
    float* wsaT  = out;                 // 2.36 MB scratch in d_out; k_apply overwrites later

    hipLaunchKernelGGL(k_alpha, dim3(256),  dim3(256), 0, stream, w, alpha);
    hipLaunchKernelGGL(k_wsaT,  dim3(2304), dim3(256), 0, stream, w, alpha, wsaT);
    hipLaunchKernelGGL(k_conv,  dim3(1024), dim3(512), 0, stream, x, wsaT, psum);
    hipLaunchKernelGGL(k_stats, dim3(16),   dim3(64),  0, stream, psum, gamma, beta, invA, btA);
    hipLaunchKernelGGL(k_apply, dim3(8192), dim3(256), 0, stream, psum, invA, btA, out);
}

// Round 5
// 1116.060 us; speedup vs baseline: 1.2030x; 1.2030x over previous
//
// v13: k_conv = v10 exactly (462µs known-good). k_stats: lane-parallel channel
// chains (8 ch/block, 128 blocks) fed by coalesced single-wave LDS staging —
// no barriers; double-buffered LDS (8x1028 rows), ping-pong 8xfloat4 chain reads.
// Per-channel FP sequence bit-identical to v8/v12. Other kernels unchanged.
#include <hip/hip_runtime.h>

#define OFF_PSUM   0UL            // 134217728 B  f32 psum[b][1024][32][32]
#define OFF_ALPHA  134217728UL    // 1024 B
#define OFF_INV    134218752UL    // 4096 B
#define OFF_BT     134222848UL    // 4096 B   (total 134.23 MB, proven fits)

// ---------------- K0a: alpha — LDS-staged, exact sequential chain ----------------
__global__ __launch_bounds__(256) void k_alpha(const float* __restrict__ w,
                                               float* __restrict__ alpha) {
#pragma clang fp contract(off)
    __shared__ float buf[2304];
    int co = blockIdx.x, t = threadIdx.x;
    const float* p = w + (size_t)co * 2304;
    for (int i = t; i < 2304; i += 256) buf[i] = p[i];
    __syncthreads();
    if (t == 0) {
        float s = 0.f;
#pragma unroll 16
        for (int k = 0; k < 2304; ++k) s = s + fabsf(buf[k]);
        alpha[co] = s / 2304.0f;
    }
}

// ---------------- K0b: transposed +-alpha table wsaT[((g*9+tap)*64+ci)*256+co] ----------------
__global__ __launch_bounds__(256) void k_wsaT(const float* __restrict__ w,
                                              const float* __restrict__ alpha,
                                              float* __restrict__ wsaT) {
    int item = blockIdx.x * 256 + threadIdx.x;     // 589824 items
    int co = item & 255;
    int rest = item >> 8;                           // 0..2303
    int ci = rest & 63;
    int t9 = rest >> 6;                             // 0..35
    int tap = t9 % 9, g = t9 / 9;
    float av = alpha[co];
    float wv = w[((size_t)co * 256 + g * 64 + ci) * 9 + tap];
    wsaT[item] = (wv >= 0.f) ? av : -av;           // exact +-alpha
}

// ---------------- K1: conv — v10: 2 px/thread, SGPR weights, 64 FMA per weight row ----------------
__global__ __launch_bounds__(512, 4) void k_conv(const float* __restrict__ x,
                                                 const float* __restrict__ wsaT,
                                                 float* __restrict__ psum) {
#pragma clang fp contract(off)
    __shared__ float xs[6][34][68];
    int bx = blockIdx.x;
    int band = bx & 7, g = (bx >> 3) & 3, b = bx >> 5;   // 1024 blocks
    int t = threadIdx.x;

    const float* xg = x + (size_t)(b * 256 + g * 64) * 1024;
#pragma unroll 1
    for (int i = 0; i < 26; ++i) {                 // 6*34*64 = 13056 elements
        int idx = i * 512 + t;
        if (idx < 13056) {
            int ci = idx & 63, col = (idx >> 6) % 34, row = idx / 2176;
            int gr = band * 4 + row - 1, gc = col - 1;
            float v = (gr >= 0 && gr < 32 && gc >= 0 && gc < 32)
                        ? xg[(size_t)ci * 1024 + gr * 32 + gc] : 0.f;
            xs[row][col][ci] = v;
        }
    }
    __syncthreads();

    int wid = t >> 6, lane = t & 63;
    int r = lane >> 5, m = lane & 31;
    int h0 = band * 4 + r;                          // second px at h0+2
    int cobase = __builtin_amdgcn_readfirstlane(wid * 32);   // wave-uniform

    float acc0[32], acc1[32];
#pragma unroll
    for (int j = 0; j < 32; ++j) { acc0[j] = 0.f; acc1[j] = 0.f; }

#pragma unroll 1
    for (int kh = 0; kh < 3; ++kh)
#pragma unroll 1
        for (int kw = 0; kw < 3; ++kw) {
            int tap = kh * 3 + kw;
            const float* bp0 = &xs[r + kh][m + kw][0];
            const float* bp1 = &xs[r + 2 + kh][m + kw][0];
            const float* wt = wsaT + (((size_t)(g * 9 + tap) * 64) << 8) + cobase;
#pragma unroll
            for (int c = 0; c < 4; ++c) {           // ci chunks of 16
                float xv0[16], xv1[16];
#pragma unroll
                for (int q = 0; q < 4; ++q) {
                    float4 a = *(const float4*)(bp0 + c * 16 + q * 4);
                    xv0[q * 4 + 0] = a.x; xv0[q * 4 + 1] = a.y;
                    xv0[q * 4 + 2] = a.z; xv0[q * 4 + 3] = a.w;
                    float4 d = *(const float4*)(bp1 + c * 16 + q * 4);
                    xv1[q * 4 + 0] = d.x; xv1[q * 4 + 1] = d.y;
                    xv1[q * 4 + 2] = d.z; xv1[q * 4 + 3] = d.w;
                }
#pragma unroll
                for (int ci = 0; ci < 16; ++ci) {   // per-acc chain order preserved
                    const float* wr = wt + ((c * 16 + ci) << 8);  // uniform -> s_load
#pragma unroll
                    for (int j = 0; j < 32; ++j)
                        acc0[j] = fmaf(xv0[ci], wr[j], acc0[j]);
#pragma unroll
                    for (int j = 0; j < 32; ++j)
                        acc1[j] = fmaf(xv1[ci], wr[j], acc1[j]);
                }
            }
        }

#pragma unroll
    for (int j = 0; j < 32; ++j) {
        int co = cobase + j;
        size_t rowo = ((size_t)b * 1024 + g * 256 + co) * 32;
        psum[(rowo + h0) * 32 + m]     = acc0[j];
        psum[(rowo + h0 + 2) * 32 + m] = acc1[j];
    }
}

// ---------------- K2: BN stats — lane-parallel chains + coalesced LDS staging ----------------
// 128 blocks x 1 wave. Block owns channels chb..chb+7; lane<8 runs channel chb+lane's
// bit-exact serial chain. Per chunk (one b): all 64 lanes coalesce-load 8x1024 floats
// into st[32] regs, chain consumes prev chunk from LDS, wave writes st -> other buffer.
// Single wave: lgkmcnt ordering, no __syncthreads.
__global__ __launch_bounds__(64, 1) void k_stats(const float* __restrict__ psum,
                                                 const float* __restrict__ gamma,
                                                 const float* __restrict__ beta,
                                                 float* __restrict__ invA,
                                                 float* __restrict__ btA) {
#pragma clang fp contract(off)
    __shared__ float ld[2][8][1028];               // 65792 B, pad 4 -> conflict-free
    int blk = blockIdx.x, lane = threadIdx.x;
    int chb = blk * 8;

    float4 st[32];

    // coalesced chunk load: per (r,q) instr, 64 lanes x 16B contiguous = 1 KB
#define LOADC(B)                                                                     \
    do { const float* _p = psum + (size_t)(B) * 1048576 + (size_t)chb * 1024;        \
        _Pragma("unroll")                                                            \
        for (int r = 0; r < 8; ++r)                                                  \
            _Pragma("unroll")                                                        \
            for (int q = 0; q < 4; ++q)                                              \
                st[r * 4 + q] = *(const float4*)(_p + r * 1024 + q * 256 + lane * 4);\
    } while (0)

#define WRITEC(BUF)                                                                  \
    do { _Pragma("unroll")                                                           \
        for (int r = 0; r < 8; ++r)                                                  \
            _Pragma("unroll")                                                        \
            for (int q = 0; q < 4; ++q)                                              \
                *(float4*)&ld[BUF][r][q * 256 + lane * 4] = st[r * 4 + q];           \
    } while (0)

    // ---- pass 1: mean (exact v8 element order: b-major, linear (h,w) within) ----
    LOADC(0);
    WRITEC(0);
    float s = 0.f;
#pragma unroll 1
    for (int b = 0; b < 32; ++b) {
        if (b + 1 < 32) LOADC(b + 1);
        __builtin_amdgcn_sched_barrier(0);
        if (lane < 8) {
            const float* row = &ld[b & 1][lane][0];
            float4 A[8], B[8];
#pragma unroll
            for (int u = 0; u < 8; ++u) A[u] = *(const float4*)(row + u * 4);
#pragma unroll 1
            for (int g = 0; g < 32; g += 2) {
                const float* p1 = row + (g + 1) * 32;
#pragma unroll
                for (int u = 0; u < 8; ++u) B[u] = *(const float4*)(p1 + u * 4);
#pragma unroll
                for (int u = 0; u < 8; ++u) {
                    s = s + A[u].x; s = s + A[u].y; s = s + A[u].z; s = s + A[u].w;
                }
                if (g + 2 < 32) {
                    const float* p2 = row + (g + 2) * 32;
#pragma unroll
                    for (int u = 0; u < 8; ++u) A[u] = *(const float4*)(p2 + u * 4);
                }
#pragma unroll
                for (int u = 0; u < 8; ++u) {
                    s = s + B[u].x; s = s + B[u].y; s = s + B[u].z; s = s + B[u].w;
                }
            }
        }
        __builtin_amdgcn_sched_barrier(0);
        if (b + 1 < 32) WRITEC((b + 1) & 1);
    }
    float mean = s / 32768.0f;

    // ---- pass 2: var — d=p-mean; q=d*d; v=v+q in exact element order ----
    LOADC(0);
    WRITEC(0);
    float v = 0.f;
#pragma unroll 1
    for (int b = 0; b < 32; ++b) {
        if (b + 1 < 32) LOADC(b + 1);
        __builtin_amdgcn_sched_barrier(0);
        if (lane < 8) {
            const float* row = &ld[b & 1][lane][0];
            float4 A[8], B[8];
#pragma unroll
            for (int u = 0; u < 8; ++u) A[u] = *(const float4*)(row + u * 4);
#pragma unroll 1
            for (int g = 0; g < 32; g += 2) {
                const float* p1 = row + (g + 1) * 32;
#pragma unroll
                for (int u = 0; u < 8; ++u) B[u] = *(const float4*)(p1 + u * 4);
#pragma unroll
                for (int u = 0; u < 8; ++u) {
                    float d0 = A[u].x - mean; float q0 = d0 * d0; v = v + q0;
                    float d1 = A[u].y - mean; float q1 = d1 * d1; v = v + q1;
                    float d2 = A[u].z - mean; float q2 = d2 * d2; v = v + q2;
                    float d3 = A[u].w - mean; float q3 = d3 * d3; v = v + q3;
                }
                if (g + 2 < 32) {
                    const float* p2 = row + (g + 2) * 32;
#pragma unroll
                    for (int u = 0; u < 8; ++u) A[u] = *(const float4*)(p2 + u * 4);
                }
#pragma unroll
                for (int u = 0; u < 8; ++u) {
                    float d0 = B[u].x - mean; float q0 = d0 * d0; v = v + q0;
                    float d1 = B[u].y - mean; float q1 = d1 * d1; v = v + q1;
                    float d2 = B[u].z - mean; float q2 = d2 * d2; v = v + q2;
                    float d3 = B[u].w - mean; float q3 = d3 * d3; v = v + q3;
                }
            }
        }
        __builtin_amdgcn_sched_barrier(0);
        if (b + 1 < 32) WRITEC((b + 1) & 1);
    }

    if (lane < 8) {
        int ch = chb + lane;
        float var = v / 32768.0f;
        float sq = sqrtf(var + 1e-5f);
        float inv = 1.0f / sq;
        inv = inv * gamma[ch];
        float mb = mean * inv;
        invA[ch] = inv;
        btA[ch] = beta[ch] - mb;
    }
#undef LOADC
#undef WRITEC
}

// ---------------- K3: BN apply + sign + merge + literal qrelu (unchanged, passed) ----------------
__global__ __launch_bounds__(256) void k_apply(const float* __restrict__ psum,
                                               const float* __restrict__ invA,
                                               const float* __restrict__ btA,
                                               float* __restrict__ out) {
#pragma clang fp contract(off)
    int idx = blockIdx.x * 256 + threadIdx.x;
    int w4 = (idx & 7) * 4;
    int hh = (idx >> 3) & 31;
    int co = (idx >> 8) & 255;
    int b  = idx >> 16;

    float s0 = 0.f, s1 = 0.f, s2 = 0.f, s3 = 0.f;
    for (int g = 0; g < 4; ++g) {
        int ch = g * 256 + co;
        const float4 p = *(const float4*)(psum + (((size_t)b * 1024 + ch) * 32 + hh) * 32 + w4);
        float iv = invA[ch], bt = btA[ch];
        float y0 = p.x * iv; y0 = y0 + bt;
        float y1 = p.y * iv; y1 = y1 + bt;
        float y2 = p.z * iv; y2 = y2 + bt;
        float y3 = p.w * iv; y3 = y3 + bt;
        s0 = s0 + ((y0 >= 0.f) ? 1.f : -1.f);
        s1 = s1 + ((y1 >= 0.f) ? 1.f : -1.f);
        s2 = s2 + ((y2 >= 0.f) ? 1.f : -1.f);
        s3 = s3 + ((y3 >= 0.f) ? 1.f : -1.f);
    }
    float4 q;
    {
        float u, rr, qq;
        u = s0 * 0.25f; u = fminf(fmaxf(u, 0.f), 1.f); rr = rintf(u * 15.f); qq = rr / 15.f; q.x = qq * 4.f;
        u = s1 * 0.25f; u = fminf(fmaxf(u, 0.f), 1.f); rr = rintf(u * 15.f); qq = rr / 15.f; q.y = qq * 4.f;
        u = s2 * 0.25f; u = fminf(fmaxf(u, 0.f), 1.f); rr = rintf(u * 15.f); qq = rr / 15.f; q.z = qq * 4.f;
        u = s3 * 0.25f; u = fminf(fmaxf(u, 0.f), 1.f); rr = rintf(u * 15.f); qq = rr / 15.f; q.w = qq * 4.f;
    }
    *(float4*)(out + (((size_t)b * 256 + co) * 32 + hh) * 32 + w4) = q;
}

extern "C" void kernel_launch(void* const* d_in, const int* in_sizes, int n_in,
                              void* d_out, int out_size, void* d_ws, size_t ws_size,
                              hipStream_t stream) {
    (void)in_sizes; (void)n_in; (void)out_size; (void)ws_size;
    const float* x     = (const float*)d_in[0];
    const float* w     = (const float*)d_in[1];
    const float* gamma = (const float*)d_in[2];
    const float* beta  = (const float*)d_in[3];
    float* out = (float*)d_out;
    char* ws = (char*)d_ws;
    float* psum  = (float*)(ws + OFF_PSUM);
    float* alpha = (float*)(ws + OFF_ALPHA);
    float* invA  = (float*)(ws + OFF_INV);
    float* btA   = (float*)(ws + OFF_BT);
    float* wsaT  = out;                 // 2.36 MB scratch in d_out; k_apply overwrites later

    hipLaunchKernelGGL(k_alpha, dim3(256),  dim3(256), 0, stream, w, alpha);
    hipLaunchKernelGGL(k_wsaT,  dim3(2304), dim3(256), 0, stream, w, alpha, wsaT);
    hipLaunchKernelGGL(k_conv,  dim3(1024), dim3(512), 0, stream, x, wsaT, psum);
    hipLaunchKernelGGL(k_stats, dim3(128),  dim3(64),  0, stream, psum, gamma, beta, invA, btA);
    hipLaunchKernelGGL(k_apply, dim3(8192), dim3(256), 0, stream, psum, invA, btA, out);
}

// Round 6
// 1033.426 us; speedup vs baseline: 1.2992x; 1.0800x over previous
//
// v14: k_conv = v10 exactly (462µs known-good). k_stats: register-staging replaced
// by global_load_lds DMA (zero staging VGPRs — kills the v13 spill), counted
// s_waitcnt vmcnt(32) one-chunk-deep pipeline, single-wave blocks (no barriers).
// Chain bodies verbatim from v13 (bit-exact v8 element order). Others unchanged.
#include <hip/hip_runtime.h>

#define OFF_PSUM   0UL            // 134217728 B  f32 psum[b][1024][32][32]
#define OFF_ALPHA  134217728UL    // 1024 B
#define OFF_INV    134218752UL    // 4096 B
#define OFF_BT     134222848UL    // 4096 B   (total 134.23 MB, proven fits)

// ---------------- K0a: alpha — LDS-staged, exact sequential chain ----------------
__global__ __launch_bounds__(256) void k_alpha(const float* __restrict__ w,
                                               float* __restrict__ alpha) {
#pragma clang fp contract(off)
    __shared__ float buf[2304];
    int co = blockIdx.x, t = threadIdx.x;
    const float* p = w + (size_t)co * 2304;
    for (int i = t; i < 2304; i += 256) buf[i] = p[i];
    __syncthreads();
    if (t == 0) {
        float s = 0.f;
#pragma unroll 16
        for (int k = 0; k < 2304; ++k) s = s + fabsf(buf[k]);
        alpha[co] = s / 2304.0f;
    }
}

// ---------------- K0b: transposed +-alpha table wsaT[((g*9+tap)*64+ci)*256+co] ----------------
__global__ __launch_bounds__(256) void k_wsaT(const float* __restrict__ w,
                                              const float* __restrict__ alpha,
                                              float* __restrict__ wsaT) {
    int item = blockIdx.x * 256 + threadIdx.x;     // 589824 items
    int co = item & 255;
    int rest = item >> 8;                           // 0..2303
    int ci = rest & 63;
    int t9 = rest >> 6;                             // 0..35
    int tap = t9 % 9, g = t9 / 9;
    float av = alpha[co];
    float wv = w[((size_t)co * 256 + g * 64 + ci) * 9 + tap];
    wsaT[item] = (wv >= 0.f) ? av : -av;           // exact +-alpha
}

// ---------------- K1: conv — v10: 2 px/thread, SGPR weights, 64 FMA per weight row ----------------
__global__ __launch_bounds__(512, 4) void k_conv(const float* __restrict__ x,
                                                 const float* __restrict__ wsaT,
                                                 float* __restrict__ psum) {
#pragma clang fp contract(off)
    __shared__ float xs[6][34][68];
    int bx = blockIdx.x;
    int band = bx & 7, g = (bx >> 3) & 3, b = bx >> 5;   // 1024 blocks
    int t = threadIdx.x;

    const float* xg = x + (size_t)(b * 256 + g * 64) * 1024;
#pragma unroll 1
    for (int i = 0; i < 26; ++i) {                 // 6*34*64 = 13056 elements
        int idx = i * 512 + t;
        if (idx < 13056) {
            int ci = idx & 63, col = (idx >> 6) % 34, row = idx / 2176;
            int gr = band * 4 + row - 1, gc = col - 1;
            float v = (gr >= 0 && gr < 32 && gc >= 0 && gc < 32)
                        ? xg[(size_t)ci * 1024 + gr * 32 + gc] : 0.f;
            xs[row][col][ci] = v;
        }
    }
    __syncthreads();

    int wid = t >> 6, lane = t & 63;
    int r = lane >> 5, m = lane & 31;
    int h0 = band * 4 + r;                          // second px at h0+2
    int cobase = __builtin_amdgcn_readfirstlane(wid * 32);   // wave-uniform

    float acc0[32], acc1[32];
#pragma unroll
    for (int j = 0; j < 32; ++j) { acc0[j] = 0.f; acc1[j] = 0.f; }

#pragma unroll 1
    for (int kh = 0; kh < 3; ++kh)
#pragma unroll 1
        for (int kw = 0; kw < 3; ++kw) {
            int tap = kh * 3 + kw;
            const float* bp0 = &xs[r + kh][m + kw][0];
            const float* bp1 = &xs[r + 2 + kh][m + kw][0];
            const float* wt = wsaT + (((size_t)(g * 9 + tap) * 64) << 8) + cobase;
#pragma unroll
            for (int c = 0; c < 4; ++c) {           // ci chunks of 16
                float xv0[16], xv1[16];
#pragma unroll
                for (int q = 0; q < 4; ++q) {
                    float4 a = *(const float4*)(bp0 + c * 16 + q * 4);
                    xv0[q * 4 + 0] = a.x; xv0[q * 4 + 1] = a.y;
                    xv0[q * 4 + 2] = a.z; xv0[q * 4 + 3] = a.w;
                    float4 d = *(const float4*)(bp1 + c * 16 + q * 4);
                    xv1[q * 4 + 0] = d.x; xv1[q * 4 + 1] = d.y;
                    xv1[q * 4 + 2] = d.z; xv1[q * 4 + 3] = d.w;
                }
#pragma unroll
                for (int ci = 0; ci < 16; ++ci) {   // per-acc chain order preserved
                    const float* wr = wt + ((c * 16 + ci) << 8);  // uniform -> s_load
#pragma unroll
                    for (int j = 0; j < 32; ++j)
                        acc0[j] = fmaf(xv0[ci], wr[j], acc0[j]);
#pragma unroll
                    for (int j = 0; j < 32; ++j)
                        acc1[j] = fmaf(xv1[ci], wr[j], acc1[j]);
                }
            }
        }

#pragma unroll
    for (int j = 0; j < 32; ++j) {
        int co = cobase + j;
        size_t rowo = ((size_t)b * 1024 + g * 256 + co) * 32;
        psum[(rowo + h0) * 32 + m]     = acc0[j];
        psum[(rowo + h0 + 2) * 32 + m] = acc1[j];
    }
}

// ---------------- K2: BN stats — lane-parallel chains + global_load_lds DMA ----------------
// 128 blocks x 1 wave; block owns channels chb..chb+7; lane<8 runs its channel's
// bit-exact serial chain. Staging: 32x global_load_lds (1KB each) per chunk, zero
// VGPRs; counted vmcnt(32) => chunk b resident while b+1 is in flight. No barriers.
typedef const __attribute__((address_space(1))) float* gas1p;
typedef __attribute__((address_space(3))) float* las3p;

__global__ __launch_bounds__(64, 1) void k_stats(const float* __restrict__ psum,
                                                 const float* __restrict__ gamma,
                                                 const float* __restrict__ beta,
                                                 float* __restrict__ invA,
                                                 float* __restrict__ btA) {
#pragma clang fp contract(off)
    __shared__ float ld[2][8][1028];               // 65792 B; +4 pad, never straddled
    int blk = blockIdx.x, lane = threadIdx.x;
    int chb = blk * 8;

    // per chunk (one b): 32 DMA instrs; LDS dest uniform base + lane*16 (linear),
    // global src uniform + lane*16 (coalesced 1KB)
#define ISSUE(B, BUF)                                                                \
    do { const float* _p = psum + (size_t)(B) * 1048576 + (size_t)chb * 1024         \
                           + (size_t)lane * 4;                                       \
        _Pragma("unroll")                                                            \
        for (int r = 0; r < 8; ++r)                                                  \
            _Pragma("unroll")                                                        \
            for (int q = 0; q < 4; ++q)                                              \
                __builtin_amdgcn_global_load_lds(                                    \
                    (const __attribute__((address_space(1))) void*)                  \
                        (_p + r * 1024 + q * 256),                                   \
                    (__attribute__((address_space(3))) void*)                        \
                        ((las3p)&ld[BUF][r][q * 256]),                               \
                    16, 0, 0);                                                       \
    } while (0)

#define WAIT32()                                                                     \
    do { __builtin_amdgcn_sched_barrier(0);                                          \
         asm volatile("s_waitcnt vmcnt(32)" ::: "memory");                           \
         __builtin_amdgcn_sched_barrier(0); } while (0)
#define WAIT0()                                                                      \
    do { __builtin_amdgcn_sched_barrier(0);                                          \
         asm volatile("s_waitcnt vmcnt(0)" ::: "memory");                            \
         __builtin_amdgcn_sched_barrier(0); } while (0)

    // ---- pass 1: mean (exact v8 element order: b-major, linear (h,w) within) ----
    ISSUE(0, 0);
    float s = 0.f;
#pragma unroll 1
    for (int b = 0; b < 32; ++b) {
        if (b + 1 < 32) { ISSUE(b + 1, (b + 1) & 1); WAIT32(); } else { WAIT0(); }
        if (lane < 8) {
            const float* row = &ld[b & 1][lane][0];
            float4 A[8], B[8];
#pragma unroll
            for (int u = 0; u < 8; ++u) A[u] = *(const float4*)(row + u * 4);
#pragma unroll 1
            for (int g = 0; g < 32; g += 2) {
                const float* p1 = row + (g + 1) * 32;
#pragma unroll
                for (int u = 0; u < 8; ++u) B[u] = *(const float4*)(p1 + u * 4);
#pragma unroll
                for (int u = 0; u < 8; ++u) {
                    s = s + A[u].x; s = s + A[u].y; s = s + A[u].z; s = s + A[u].w;
                }
                if (g + 2 < 32) {
                    const float* p2 = row + (g + 2) * 32;
#pragma unroll
                    for (int u = 0; u < 8; ++u) A[u] = *(const float4*)(p2 + u * 4);
                }
#pragma unroll
                for (int u = 0; u < 8; ++u) {
                    s = s + B[u].x; s = s + B[u].y; s = s + B[u].z; s = s + B[u].w;
                }
            }
        }
        __builtin_amdgcn_sched_barrier(0);
    }
    float mean = s / 32768.0f;

    // ---- pass 2: var — d=p-mean; q=d*d; v=v+q in exact element order ----
    ISSUE(0, 0);
    float v = 0.f;
#pragma unroll 1
    for (int b = 0; b < 32; ++b) {
        if (b + 1 < 32) { ISSUE(b + 1, (b + 1) & 1); WAIT32(); } else { WAIT0(); }
        if (lane < 8) {
            const float* row = &ld[b & 1][lane][0];
            float4 A[8], B[8];
#pragma unroll
            for (int u = 0; u < 8; ++u) A[u] = *(const float4*)(row + u * 4);
#pragma unroll 1
            for (int g = 0; g < 32; g += 2) {
                const float* p1 = row + (g + 1) * 32;
#pragma unroll
                for (int u = 0; u < 8; ++u) B[u] = *(const float4*)(p1 + u * 4);
#pragma unroll
                for (int u = 0; u < 8; ++u) {
                    float d0 = A[u].x - mean; float q0 = d0 * d0; v = v + q0;
                    float d1 = A[u].y - mean; float q1 = d1 * d1; v = v + q1;
                    float d2 = A[u].z - mean; float q2 = d2 * d2; v = v + q2;
                    float d3 = A[u].w - mean; float q3 = d3 * d3; v = v + q3;
                }
                if (g + 2 < 32) {
                    const float* p2 = row + (g + 2) * 32;
#pragma unroll
                    for (int u = 0; u < 8; ++u) A[u] = *(const float4*)(p2 + u * 4);
                }
#pragma unroll
                for (int u = 0; u < 8; ++u) {
                    float d0 = B[u].x - mean; float q0 = d0 * d0; v = v + q0;
                    float d1 = B[u].y - mean; float q1 = d1 * d1; v = v + q1;
                    float d2 = B[u].z - mean; float q2 = d2 * d2; v = v + q2;
                    float d3 = B[u].w - mean; float q3 = d3 * d3; v = v + q3;
                }
            }
        }
        __builtin_amdgcn_sched_barrier(0);
    }

    if (lane < 8) {
        int ch = chb + lane;
        float var = v / 32768.0f;
        float sq = sqrtf(var + 1e-5f);
        float inv = 1.0f / sq;
        inv = inv * gamma[ch];
        float mb = mean * inv;
        invA[ch] = inv;
        btA[ch] = beta[ch] - mb;
    }
#undef ISSUE
#undef WAIT32
#undef WAIT0
}

// ---------------- K3: BN apply + sign + merge + literal qrelu (unchanged, passed) ----------------
__global__ __launch_bounds__(256) void k_apply(const float* __restrict__ psum,
                                               const float* __restrict__ invA,
                                               const float* __restrict__ btA,
                                               float* __restrict__ out) {
#pragma clang fp contract(off)
    int idx = blockIdx.x * 256 + threadIdx.x;
    int w4 = (idx & 7) * 4;
    int hh = (idx >> 3) & 31;
    int co = (idx >> 8) & 255;
    int b  = idx >> 16;

    float s0 = 0.f, s1 = 0.f, s2 = 0.f, s3 = 0.f;
    for (int g = 0; g < 4; ++g) {
        int ch = g * 256 + co;
        const float4 p = *(const float4*)(psum + (((size_t)b * 1024 + ch) * 32 + hh) * 32 + w4);
        float iv = invA[ch], bt = btA[ch];
        float y0 = p.x * iv; y0 = y0 + bt;
        float y1 = p.y * iv; y1 = y1 + bt;
        float y2 = p.z * iv; y2 = y2 + bt;
        float y3 = p.w * iv; y3 = y3 + bt;
        s0 = s0 + ((y0 >= 0.f) ? 1.f : -1.f);
        s1 = s1 + ((y1 >= 0.f) ? 1.f : -1.f);
        s2 = s2 + ((y2 >= 0.f) ? 1.f : -1.f);
        s3 = s3 + ((y3 >= 0.f) ? 1.f : -1.f);
    }
    float4 q;
    {
        float u, rr, qq;
        u = s0 * 0.25f; u = fminf(fmaxf(u, 0.f), 1.f); rr = rintf(u * 15.f); qq = rr / 15.f; q.x = qq * 4.f;
        u = s1 * 0.25f; u = fminf(fmaxf(u, 0.f), 1.f); rr = rintf(u * 15.f); qq = rr / 15.f; q.y = qq * 4.f;
        u = s2 * 0.25f; u = fminf(fmaxf(u, 0.f), 1.f); rr = rintf(u * 15.f); qq = rr / 15.f; q.z = qq * 4.f;
        u = s3 * 0.25f; u = fminf(fmaxf(u, 0.f), 1.f); rr = rintf(u * 15.f); qq = rr / 15.f; q.w = qq * 4.f;
    }
    *(float4*)(out + (((size_t)b * 256 + co) * 32 + hh) * 32 + w4) = q;
}

extern "C" void kernel_launch(void* const* d_in, const int* in_sizes, int n_in,
                              void* d_out, int out_size, void* d_ws, size_t ws_size,
                              hipStream_t stream) {
    (void)in_sizes; (void)n_in; (void)out_size; (void)ws_size;
    const float* x     = (const float*)d_in[0];
    const float* w     = (const float*)d_in[1];
    const float* gamma = (const float*)d_in[2];
    const float* beta  = (const float*)d_in[3];
    float* out = (float*)d_out;
    char* ws = (char*)d_ws;
    float* psum  = (float*)(ws + OFF_PSUM);
    float* alpha = (float*)(ws + OFF_ALPHA);
    float* invA  = (float*)(ws + OFF_INV);
    float* btA   = (float*)(ws + OFF_BT);
    float* wsaT  = out;                 // 2.36 MB scratch in d_out; k_apply overwrites later

    hipLaunchKernelGGL(k_alpha, dim3(256),  dim3(256), 0, stream, w, alpha);
    hipLaunchKernelGGL(k_wsaT,  dim3(2304), dim3(256), 0, stream, w, alpha, wsaT);
    hipLaunchKernelGGL(k_conv,  dim3(1024), dim3(512), 0, stream, x, wsaT, psum);
    hipLaunchKernelGGL(k_stats, dim3(128),  dim3(64),  0, stream, psum, gamma, beta, invA, btA);
    hipLaunchKernelGGL(k_apply, dim3(8192), dim3(256), 0, stream, psum, invA, btA, out);
}

// Round 7
// 800.435 us; speedup vs baseline: 1.6773x; 1.2911x over previous
//
// v15: k_conv = v10 (462µs known-good). k_stats rebuilt: 512 blocks x 2ch,
// depth-3 global_load_lds prefetch over 4 LDS buffers (counted vmcnt 24/16/8/0),
// chain reads via inline-asm ds_read_b128 (invisible to the memory legalizer —
// no compiler-inserted vmcnt(0) drain) with counted lgkmcnt(8) ping-pong and
// sched_barrier pins. Per-channel FP chain order bit-identical to v8..v14.
#include <hip/hip_runtime.h>

#define OFF_PSUM   0UL            // 134217728 B  f32 psum[b][1024][32][32]
#define OFF_ALPHA  134217728UL    // 1024 B
#define OFF_INV    134218752UL    // 4096 B
#define OFF_BT     134222848UL    // 4096 B   (total 134.23 MB, proven fits)

// ---------------- K0a: alpha — LDS-staged, exact sequential chain ----------------
__global__ __launch_bounds__(256) void k_alpha(const float* __restrict__ w,
                                               float* __restrict__ alpha) {
#pragma clang fp contract(off)
    __shared__ float buf[2304];
    int co = blockIdx.x, t = threadIdx.x;
    const float* p = w + (size_t)co * 2304;
    for (int i = t; i < 2304; i += 256) buf[i] = p[i];
    __syncthreads();
    if (t == 0) {
        float s = 0.f;
#pragma unroll 16
        for (int k = 0; k < 2304; ++k) s = s + fabsf(buf[k]);
        alpha[co] = s / 2304.0f;
    }
}

// ---------------- K0b: transposed +-alpha table wsaT[((g*9+tap)*64+ci)*256+co] ----------------
__global__ __launch_bounds__(256) void k_wsaT(const float* __restrict__ w,
                                              const float* __restrict__ alpha,
                                              float* __restrict__ wsaT) {
    int item = blockIdx.x * 256 + threadIdx.x;     // 589824 items
    int co = item & 255;
    int rest = item >> 8;                           // 0..2303
    int ci = rest & 63;
    int t9 = rest >> 6;                             // 0..35
    int tap = t9 % 9, g = t9 / 9;
    float av = alpha[co];
    float wv = w[((size_t)co * 256 + g * 64 + ci) * 9 + tap];
    wsaT[item] = (wv >= 0.f) ? av : -av;           // exact +-alpha
}

// ---------------- K1: conv — v10: 2 px/thread, SGPR weights, 64 FMA per weight row ----------------
__global__ __launch_bounds__(512, 4) void k_conv(const float* __restrict__ x,
                                                 const float* __restrict__ wsaT,
                                                 float* __restrict__ psum) {
#pragma clang fp contract(off)
    __shared__ float xs[6][34][68];
    int bx = blockIdx.x;
    int band = bx & 7, g = (bx >> 3) & 3, b = bx >> 5;   // 1024 blocks
    int t = threadIdx.x;

    const float* xg = x + (size_t)(b * 256 + g * 64) * 1024;
#pragma unroll 1
    for (int i = 0; i < 26; ++i) {                 // 6*34*64 = 13056 elements
        int idx = i * 512 + t;
        if (idx < 13056) {
            int ci = idx & 63, col = (idx >> 6) % 34, row = idx / 2176;
            int gr = band * 4 + row - 1, gc = col - 1;
            float v = (gr >= 0 && gr < 32 && gc >= 0 && gc < 32)
                        ? xg[(size_t)ci * 1024 + gr * 32 + gc] : 0.f;
            xs[row][col][ci] = v;
        }
    }
    __syncthreads();

    int wid = t >> 6, lane = t & 63;
    int r = lane >> 5, m = lane & 31;
    int h0 = band * 4 + r;                          // second px at h0+2
    int cobase = __builtin_amdgcn_readfirstlane(wid * 32);   // wave-uniform

    float acc0[32], acc1[32];
#pragma unroll
    for (int j = 0; j < 32; ++j) { acc0[j] = 0.f; acc1[j] = 0.f; }

#pragma unroll 1
    for (int kh = 0; kh < 3; ++kh)
#pragma unroll 1
        for (int kw = 0; kw < 3; ++kw) {
            int tap = kh * 3 + kw;
            const float* bp0 = &xs[r + kh][m + kw][0];
            const float* bp1 = &xs[r + 2 + kh][m + kw][0];
            const float* wt = wsaT + (((size_t)(g * 9 + tap) * 64) << 8) + cobase;
#pragma unroll
            for (int c = 0; c < 4; ++c) {           // ci chunks of 16
                float xv0[16], xv1[16];
#pragma unroll
                for (int q = 0; q < 4; ++q) {
                    float4 a = *(const float4*)(bp0 + c * 16 + q * 4);
                    xv0[q * 4 + 0] = a.x; xv0[q * 4 + 1] = a.y;
                    xv0[q * 4 + 2] = a.z; xv0[q * 4 + 3] = a.w;
                    float4 d = *(const float4*)(bp1 + c * 16 + q * 4);
                    xv1[q * 4 + 0] = d.x; xv1[q * 4 + 1] = d.y;
                    xv1[q * 4 + 2] = d.z; xv1[q * 4 + 3] = d.w;
                }
#pragma unroll
                for (int ci = 0; ci < 16; ++ci) {   // per-acc chain order preserved
                    const float* wr = wt + ((c * 16 + ci) << 8);  // uniform -> s_load
#pragma unroll
                    for (int j = 0; j < 32; ++j)
                        acc0[j] = fmaf(xv0[ci], wr[j], acc0[j]);
#pragma unroll
                    for (int j = 0; j < 32; ++j)
                        acc1[j] = fmaf(xv1[ci], wr[j], acc1[j]);
                }
            }
        }

#pragma unroll
    for (int j = 0; j < 32; ++j) {
        int co = cobase + j;
        size_t rowo = ((size_t)b * 1024 + g * 256 + co) * 32;
        psum[(rowo + h0) * 32 + m]     = acc0[j];
        psum[(rowo + h0 + 2) * 32 + m] = acc1[j];
    }
}

// ---------------- K2: BN stats — asm-pinned lane chains, depth-3 DMA ----------------
typedef float f4 __attribute__((ext_vector_type(4)));

__global__ __launch_bounds__(64, 1) void k_stats(const float* __restrict__ psum,
                                                 const float* __restrict__ gamma,
                                                 const float* __restrict__ beta,
                                                 float* __restrict__ invA,
                                                 float* __restrict__ btA) {
#pragma clang fp contract(off)
    __shared__ float ld[4][2][1028];               // 32896 B; 4 bufs x 2 ch, +4 pad
    int blk = blockIdx.x, lane = threadIdx.x;
    int chb = blk * 2;

    // lane-dependent 32-bit LDS byte base for chain reads (row = lane&1)
    unsigned lbase;
    {
        __attribute__((address_space(3))) float* lp =
            (__attribute__((address_space(3))) float*)&ld[0][lane & 1][0];
        lbase = (unsigned)(unsigned long long)lp;
    }

#define ISSUE(B, BUF)                                                                \
    do { const float* _p = psum + (size_t)(B) * 1048576 + (size_t)chb * 1024         \
                           + (size_t)lane * 4;                                       \
        _Pragma("unroll")                                                            \
        for (int r = 0; r < 2; ++r)                                                  \
            _Pragma("unroll")                                                        \
            for (int q = 0; q < 4; ++q)                                              \
                __builtin_amdgcn_global_load_lds(                                    \
                    (const __attribute__((address_space(1))) void*)                  \
                        (_p + r * 1024 + q * 256),                                   \
                    (__attribute__((address_space(3))) void*)                        \
                        ((__attribute__((address_space(3))) float*)                  \
                            &ld[BUF][r][q * 256]),                                   \
                    16, 0, 0);                                                       \
    } while (0)

#define WVM(N)                                                                       \
    do { __builtin_amdgcn_sched_barrier(0);                                          \
         asm volatile("s_waitcnt vmcnt(" #N ")" ::: "memory");                       \
         __builtin_amdgcn_sched_barrier(0); } while (0)

#define WLG(N)                                                                       \
    do { asm volatile("s_waitcnt lgkmcnt(" #N ")" :::);                              \
         __builtin_amdgcn_sched_barrier(0); } while (0)

#define DSR8(P0,P1,P2,P3,P4,P5,P6,P7, G, RA)                                         \
    do {                                                                             \
        asm volatile("ds_read_b128 %0, %1 offset:%c2" : "=v"(P0) : "v"(RA), "i"((G)*128 +   0)); \
        asm volatile("ds_read_b128 %0, %1 offset:%c2" : "=v"(P1) : "v"(RA), "i"((G)*128 +  16)); \
        asm volatile("ds_read_b128 %0, %1 offset:%c2" : "=v"(P2) : "v"(RA), "i"((G)*128 +  32)); \
        asm volatile("ds_read_b128 %0, %1 offset:%c2" : "=v"(P3) : "v"(RA), "i"((G)*128 +  48)); \
        asm volatile("ds_read_b128 %0, %1 offset:%c2" : "=v"(P4) : "v"(RA), "i"((G)*128 +  64)); \
        asm volatile("ds_read_b128 %0, %1 offset:%c2" : "=v"(P5) : "v"(RA), "i"((G)*128 +  80)); \
        asm volatile("ds_read_b128 %0, %1 offset:%c2" : "=v"(P6) : "v"(RA), "i"((G)*128 +  96)); \
        asm volatile("ds_read_b128 %0, %1 offset:%c2" : "=v"(P7) : "v"(RA), "i"((G)*128 + 112)); \
    } while (0)

#define SUM4(V)  do { s = s + (V).x; s = s + (V).y; s = s + (V).z; s = s + (V).w; } while (0)
#define SUM8(Q0,Q1,Q2,Q3,Q4,Q5,Q6,Q7)                                                \
    do { SUM4(Q0); SUM4(Q1); SUM4(Q2); SUM4(Q3);                                     \
         SUM4(Q4); SUM4(Q5); SUM4(Q6); SUM4(Q7); } while (0)

#define VAR4(V)                                                                      \
    do { float d0 = (V).x - mean; float q0 = d0 * d0; v = v + q0;                    \
         float d1 = (V).y - mean; float q1 = d1 * d1; v = v + q1;                    \
         float d2 = (V).z - mean; float q2 = d2 * d2; v = v + q2;                    \
         float d3 = (V).w - mean; float q3 = d3 * d3; v = v + q3; } while (0)
#define VAR8(Q0,Q1,Q2,Q3,Q4,Q5,Q6,Q7)                                                \
    do { VAR4(Q0); VAR4(Q1); VAR4(Q2); VAR4(Q3);                                     \
         VAR4(Q4); VAR4(Q5); VAR4(Q6); VAR4(Q7); } while (0)

    // ---- pass 1: mean (exact v8 element order: b-major, linear (h,w) within) ----
    ISSUE(0, 0); ISSUE(1, 1); ISSUE(2, 2);
    float s = 0.f;
#pragma unroll 1
    for (int b = 0; b < 32; ++b) {
        if (b + 3 < 32)      { ISSUE(b + 3, (b + 3) & 3); WVM(24); }
        else if (b == 29)    { WVM(16); }
        else if (b == 30)    { WVM(8);  }
        else                 { WVM(0);  }
        unsigned ra = lbase + (unsigned)((b & 3) * 8224);
        f4 A0,A1,A2,A3,A4,A5,A6,A7, B0,B1,B2,B3,B4,B5,B6,B7;
        DSR8(A0,A1,A2,A3,A4,A5,A6,A7, 0, ra);
#pragma unroll
        for (int g = 0; g < 32; g += 2) {
            DSR8(B0,B1,B2,B3,B4,B5,B6,B7, g + 1, ra);
            WLG(8);
            SUM8(A0,A1,A2,A3,A4,A5,A6,A7);
            if (g + 2 < 32) { DSR8(A0,A1,A2,A3,A4,A5,A6,A7, g + 2, ra); WLG(8); }
            else            { WLG(0); }
            SUM8(B0,B1,B2,B3,B4,B5,B6,B7);
        }
    }
    float mean = s / 32768.0f;

    // ---- pass 2: var — d=p-mean; q=d*d; v=v+q in exact element order ----
    ISSUE(0, 0); ISSUE(1, 1); ISSUE(2, 2);
    float v = 0.f;
#pragma unroll 1
    for (int b = 0; b < 32; ++b) {
        if (b + 3 < 32)      { ISSUE(b + 3, (b + 3) & 3); WVM(24); }
        else if (b == 29)    { WVM(16); }
        else if (b == 30)    { WVM(8);  }
        else                 { WVM(0);  }
        unsigned ra = lbase + (unsigned)((b & 3) * 8224);
        f4 A0,A1,A2,A3,A4,A5,A6,A7, B0,B1,B2,B3,B4,B5,B6,B7;
        DSR8(A0,A1,A2,A3,A4,A5,A6,A7, 0, ra);
#pragma unroll
        for (int g = 0; g < 32; g += 2) {
            DSR8(B0,B1,B2,B3,B4,B5,B6,B7, g + 1, ra);
            WLG(8);
            VAR8(A0,A1,A2,A3,A4,A5,A6,A7);
            if (g + 2 < 32) { DSR8(A0,A1,A2,A3,A4,A5,A6,A7, g + 2, ra); WLG(8); }
            else            { WLG(0); }
            VAR8(B0,B1,B2,B3,B4,B5,B6,B7);
        }
    }

    if (lane < 2) {
        int ch = chb + lane;
        float var = v / 32768.0f;
        float sq = sqrtf(var + 1e-5f);
        float inv = 1.0f / sq;
        inv = inv * gamma[ch];
        float mb = mean * inv;
        invA[ch] = inv;
        btA[ch] = beta[ch] - mb;
    }
#undef ISSUE
#undef WVM
#undef WLG
#undef DSR8
#undef SUM4
#undef SUM8
#undef VAR4
#undef VAR8
}

// ---------------- K3: BN apply + sign + merge + literal qrelu (unchanged, passed) ----------------
__global__ __launch_bounds__(256) void k_apply(const float* __restrict__ psum,
                                               const float* __restrict__ invA,
                                               const float* __restrict__ btA,
                                               float* __restrict__ out) {
#pragma clang fp contract(off)
    int idx = blockIdx.x * 256 + threadIdx.x;
    int w4 = (idx & 7) * 4;
    int hh = (idx >> 3) & 31;
    int co = (idx >> 8) & 255;
    int b  = idx >> 16;

    float s0 = 0.f, s1 = 0.f, s2 = 0.f, s3 = 0.f;
    for (int g = 0; g < 4; ++g) {
        int ch = g * 256 + co;
        const float4 p = *(const float4*)(psum + (((size_t)b * 1024 + ch) * 32 + hh) * 32 + w4);
        float iv = invA[ch], bt = btA[ch];
        float y0 = p.x * iv; y0 = y0 + bt;
        float y1 = p.y * iv; y1 = y1 + bt;
        float y2 = p.z * iv; y2 = y2 + bt;
        float y3 = p.w * iv; y3 = y3 + bt;
        s0 = s0 + ((y0 >= 0.f) ? 1.f : -1.f);
        s1 = s1 + ((y1 >= 0.f) ? 1.f : -1.f);
        s2 = s2 + ((y2 >= 0.f) ? 1.f : -1.f);
        s3 = s3 + ((y3 >= 0.f) ? 1.f : -1.f);
    }
    float4 q;
    {
        float u, rr, qq;
        u = s0 * 0.25f; u = fminf(fmaxf(u, 0.f), 1.f); rr = rintf(u * 15.f); qq = rr / 15.f; q.x = qq * 4.f;
        u = s1 * 0.25f; u = fminf(fmaxf(u, 0.f), 1.f); rr = rintf(u * 15.f); qq = rr / 15.f; q.y = qq * 4.f;
        u = s2 * 0.25f; u = fminf(fmaxf(u, 0.f), 1.f); rr = rintf(u * 15.f); qq = rr / 15.f; q.z = qq * 4.f;
        u = s3 * 0.25f; u = fminf(fmaxf(u, 0.f), 1.f); rr = rintf(u * 15.f); qq = rr / 15.f; q.w = qq * 4.f;
    }
    *(float4*)(out + (((size_t)b * 256 + co) * 32 + hh) * 32 + w4) = q;
}

extern "C" void kernel_launch(void* const* d_in, const int* in_sizes, int n_in,
                              void* d_out, int out_size, void* d_ws, size_t ws_size,
                              hipStream_t stream) {
    (void)in_sizes; (void)n_in; (void)out_size; (void)ws_size;
    const float* x     = (const float*)d_in[0];
    const float* w     = (const float*)d_in[1];
    const float* gamma = (const float*)d_in[2];
    const float* beta  = (const float*)d_in[3];
    float* out = (float*)d_out;
    char* ws = (char*)d_ws;
    float* psum  = (float*)(ws + OFF_PSUM);
    float* alpha = (float*)(ws + OFF_ALPHA);
    float* invA  = (float*)(ws + OFF_INV);
    float* btA   = (float*)(ws + OFF_BT);
    float* wsaT  = out;                 // 2.36 MB scratch in d_out; k_apply overwrites later

    hipLaunchKernelGGL(k_alpha, dim3(256),  dim3(256), 0, stream, w, alpha);
    hipLaunchKernelGGL(k_wsaT,  dim3(2304), dim3(256), 0, stream, w, alpha, wsaT);
    hipLaunchKernelGGL(k_conv,  dim3(1024), dim3(512), 0, stream, x, wsaT, psum);
    hipLaunchKernelGGL(k_stats, dim3(512),  dim3(64),  0, stream, psum, gamma, beta, invA, btA);
    hipLaunchKernelGGL(k_apply, dim3(8192), dim3(256), 0, stream, psum, invA, btA, out);
}